// Round 11
// baseline (16266.675 us; speedup 1.0000x reference)
//
#include <hip/hip_runtime.h>
#include <math.h>

#pragma clang fp contract(off)

#define NB 2048
#define NC 1000
#define NK 2048
#define RPB 4                  // rows per block (parallel thread-groups)
#define NBLK (NB / RPB)        // 512 blocks = 2 blocks/CU * 256 CUs (guaranteed co-resident)

typedef unsigned long long u64;

// ---------------- GEMM: fp32 fold-left ascending-k with K-panel folds of PC chunks ------
__global__ __launch_bounds__(256) void k_gemm(const float* __restrict__ x,
                                              const float* __restrict__ W,
                                              const float* __restrict__ bias,
                                              float* __restrict__ z, int PC) {
    __shared__ float As[16][64];
    __shared__ float Bs[16][64];
    const int tid = threadIdx.x;
    const int m0 = blockIdx.y * 64, n0 = blockIdx.x * 64;
    const int tx = tid & 15, ty = tid >> 4;
    float accT[4][4];
    float accB[4][4];
#pragma unroll
    for (int i = 0; i < 4; i++)
#pragma unroll
        for (int j = 0; j < 4; j++) { accT[i][j] = 0.0f; accB[i][j] = 0.0f; }

    for (int kb = 0; kb < 128; kb++) {
        if (PC > 0 && kb > 0 && (kb % PC) == 0) {
#pragma unroll
            for (int i = 0; i < 4; i++)
#pragma unroll
                for (int j = 0; j < 4; j++) { accT[i][j] += accB[i][j]; accB[i][j] = 0.0f; }
        }
        const int k0 = kb * 16;
        {
            int row = tid >> 2, kg = tid & 3;
            const float4 a = *(const float4*)(x + (size_t)(m0 + row) * NK + k0 + kg * 4);
            As[kg * 4 + 0][row] = a.x;
            As[kg * 4 + 1][row] = a.y;
            As[kg * 4 + 2][row] = a.z;
            As[kg * 4 + 3][row] = a.w;
        }
        {
            int rowk = tid >> 4, c4 = tid & 15;
            int cbase = n0 + c4 * 4;
            const float* wp = W + (size_t)(k0 + rowk) * NC + cbase;
#pragma unroll
            for (int j = 0; j < 4; j++)
                Bs[rowk][c4 * 4 + j] = (cbase + j < NC) ? wp[j] : 0.0f;
        }
        __syncthreads();
#pragma unroll
        for (int kk = 0; kk < 16; kk++) {
            float a[4], bb[4];
#pragma unroll
            for (int i = 0; i < 4; i++) a[i] = As[kk][ty * 4 + i];
#pragma unroll
            for (int j = 0; j < 4; j++) bb[j] = Bs[kk][tx * 4 + j];
#pragma unroll
            for (int i = 0; i < 4; i++)
#pragma unroll
                for (int j = 0; j < 4; j++) accB[i][j] = fmaf(a[i], bb[j], accB[i][j]);
        }
        __syncthreads();
    }
#pragma unroll
    for (int i = 0; i < 4; i++) {
        int r = m0 + ty * 4 + i;
#pragma unroll
        for (int j = 0; j < 4; j++) {
            int c = n0 + tx * 4 + j;
            if (c < NC) {
                float s = accT[i][j] + accB[i][j];
                z[(size_t)r * NC + c] = s + bias[c];
            }
        }
    }
}

// ---------------- per-row stats ----------------
__global__ __launch_bounds__(256) void k_rowstats(const float* __restrict__ z,
                                                  int* __restrict__ y,
                                                  float* __restrict__ ptrg,
                                                  float* __restrict__ se,
                                                  float* __restrict__ rm,
                                                  int* __restrict__ am) {
    __shared__ float sv[256];
    __shared__ int si[256];
    const int tid = threadIdx.x, row = blockIdx.x;
    const float* zr = z + (size_t)row * NC;
    float bv = -INFINITY;
    int bi = 0x7fffffff;
    for (int c = tid; c < NC; c += 256) {
        float zz = zr[c];
        if (zz > bv) { bv = zz; bi = c; }
    }
    sv[tid] = bv; si[tid] = bi;
    __syncthreads();
    for (int s = 128; s > 0; s >>= 1) {
        if (tid < s) {
            float v2 = sv[tid + s]; int i2 = si[tid + s];
            if (v2 > sv[tid] || (v2 == sv[tid] && i2 < si[tid])) { sv[tid] = v2; si[tid] = i2; }
        }
        __syncthreads();
    }
    const float rmx = sv[0];
    const int amx = si[0];
    __syncthreads();
    float sl = 0.0f;
    for (int c = tid; c < NC; c += 256) sl += expf(zr[c] - rmx);
    sv[tid] = sl;
    __syncthreads();
    for (int s = 128; s > 0; s >>= 1) {
        if (tid < s) sv[tid] += sv[tid + s];
        __syncthreads();
    }
    if (tid == 0) {
        float s0 = sv[0];
        y[row] = amx; ptrg[row] = 1.0f / s0;
        se[row] = s0; rm[row] = rmx; am[row] = amx;
    }
}

__global__ void k_hist(const int* __restrict__ y, int* __restrict__ cnt) {
    int i = blockIdx.x * 256 + threadIdx.x;
    if (i < NB) atomicAdd(&cnt[y[i]], 1);
}
__global__ __launch_bounds__(1024) void k_group(const int* __restrict__ y,
                                                const int* __restrict__ cnt,
                                                int* __restrict__ off,
                                                int* __restrict__ pos,
                                                int* __restrict__ jidx,
                                                int* __restrict__ pinv) {
    __shared__ int s[1024];
    const int tid = threadIdx.x;
    int myc = (tid < NC) ? cnt[tid] : 0;
    s[tid] = myc;
    __syncthreads();
    for (int d = 1; d < 1024; d <<= 1) {
        int add = (tid >= d) ? s[tid - d] : 0;
        __syncthreads();
        s[tid] += add;
        __syncthreads();
    }
    if (tid < NC) {
        int excl = s[tid] - myc;
        off[tid] = excl;
        pos[tid] = excl;
    }
    if (tid == 0) off[NC] = NB;
    __syncthreads();
    for (int j = tid; j < NB; j += 1024) {
        int c = y[j];
        int p = atomicAdd(&pos[c], 1);
        jidx[p] = j;
        pinv[j] = p;
    }
}

// ---------------- bitonic sort of ptrg (2048) -> ptrgS, once per pass ----------------
__global__ __launch_bounds__(1024) void k_sort(const float* __restrict__ ptrg,
                                               float* __restrict__ ptrgS) {
    __shared__ float ps[2048];
    const int tid = threadIdx.x;
    ps[tid] = ptrg[tid];
    ps[tid + 1024] = ptrg[tid + 1024];
    __syncthreads();
    for (int k = 2; k <= 2048; k <<= 1) {
        for (int j = k >> 1; j > 0; j >>= 1) {
            int i1 = ((tid & ~(j - 1)) << 1) | (tid & (j - 1));
            int i2 = i1 | j;
            bool up = ((i1 & k) == 0);
            float a = ps[i1], b = ps[i2];
            if ((a > b) == up) { ps[i1] = b; ps[i2] = a; }
            __syncthreads();
        }
    }
    ptrgS[tid] = ps[tid];
    ptrgS[tid + 1024] = ps[tid + 1024];
}

// tz + initial permuted tu
__global__ __launch_bounds__(256) void k_preptz(const float* __restrict__ z,
                                                const int* __restrict__ cnt,
                                                const int* __restrict__ pinv,
                                                float* __restrict__ tz,
                                                float* __restrict__ tuP) {
    __shared__ float sv[256];
    const int tid = threadIdx.x, row = blockIdx.x;
    const float* zr = z + (size_t)row * NC;
    float tm = -1000.0f;
    for (int c = tid; c < NC; c += 256) {
        float zz = zr[c];
        if (cnt[c] == 0) tm = fmaxf(tm, zz);
    }
    sv[tid] = tm;
    __syncthreads();
    for (int s = 128; s > 0; s >>= 1) {
        if (tid < s) sv[tid] = fmaxf(sv[tid], sv[tid + s]);
        __syncthreads();
    }
    if (tid == 0) { tz[row] = sv[0]; tuP[pinv[row]] = sv[0]; }
}

__global__ __launch_bounds__(256) void k_thr(const float* __restrict__ z,
                                             const float* __restrict__ tz,
                                             const int* __restrict__ y,
                                             const int* __restrict__ jidx,
                                             float* __restrict__ ThrG) {
    const int tid = threadIdx.x, a = blockIdx.x;
    const float PIF = 3.14159265358979323846f;
    const float* zr = z + (size_t)a * NC;
    for (int p = tid; p < NB; p += 256) {
        int j = jidx[p];
        int c = y[j];
        float L = zr[c] - tz[j];
        float q = L / 6.0f;
        float fq = floorf(q);
        float fh = fq + 0.5f;
        float latr = fh * 6.0f;
        float d1 = L - latr;
        float d2 = 2.0f * d1;
        float d3 = d2 / 6.0f;
        float d4 = 1.0f - d3;
        float d5 = PIF * d4;
        float sn = sinf(d5);
        float p6 = 6.0f * sn;
        float thr = L - p6;
        ThrG[(size_t)a * NB + p] = thr;
    }
}

// -------- agent-scope (device-coherent) access helpers --------
__device__ __forceinline__ float ldgA(const float* p) {
    return __hip_atomic_load(p, __ATOMIC_RELAXED, __HIP_MEMORY_SCOPE_AGENT);
}
__device__ __forceinline__ int ldgAi(const int* p) {
    return __hip_atomic_load(p, __ATOMIC_RELAXED, __HIP_MEMORY_SCOPE_AGENT);
}
__device__ __forceinline__ u64 ldgAu64(const u64* p) {
    return __hip_atomic_load(p, __ATOMIC_RELAXED, __HIP_MEMORY_SCOPE_AGENT);
}
__device__ __forceinline__ void stgA(float* p, float v) {
    __hip_atomic_store(p, v, __ATOMIC_RELAXED, __HIP_MEMORY_SCOPE_AGENT);
}

// ---------------- all 100 Adam steps; 4 rows/block; FLAT grid barrier -----------------
// Round-7 compute structure. Barrier flattened for 512 arrivals: each block's leader
// atomicMax's its key into rootKey[t] then counted-adds rootCnt[t]; all blocks poll the
// single counter word (read-only; RMW storms, not read storms, are what melt L3) and
// then read the final key. Chain: max -> add -> poll-detect -> key-read (~3 hops) vs the
// old 2-level tree's ~5. Same key set -> same max -> bit-identical scalars.
__global__ __launch_bounds__(1024, 8) void k_adam(
    const float* __restrict__ z0,
    float* __restrict__ uout,
    const float* __restrict__ ThrG,
    const float* __restrict__ ptrg,
    const float* __restrict__ ptrgS,
    const int* __restrict__ cnt,
    const int* __restrict__ off,
    const int* __restrict__ jidx,
    const int* __restrict__ pinv,
    const float* __restrict__ seA, const float* __restrict__ rmA,
    const int* __restrict__ amA,
    float* __restrict__ tuPA, float* __restrict__ tuPB,
    const float* __restrict__ bcT,
    int* __restrict__ rootCnt, u64* __restrict__ rootKey) {
    __shared__ float tuLs[NB];            // permuted tu, shared by 4 rows (8 KB)
    __shared__ float thrL[RPB][NB];       // 4 ThrG rows, staged ONCE (32 KB)
    __shared__ float svg[RPB][256];
    __shared__ int   sig[RPB][256];
    __shared__ float tvg[RPB][256];
    __shared__ float sc[RPB][3];          // coef, se_i, rm_i per row
    __shared__ int   sci[RPB][2];         // jstar, istar per row
    __shared__ float outRmG[RPB];
    __shared__ u64   kB[RPB];
    __shared__ u64   kShared;
    const int tid = threadIdx.x;
    const int g = tid >> 8;               // row group 0..3
    const int l = tid & 255;              // lane within group
    const int row = blockIdx.x * RPB + g;
    const float B1F = 0.9f;
    const float C1 = (float)(1.0 - 0.9);
    const float B2F = 0.999f;
    const float C2 = (float)(1.0 - 0.999);

    float U[4], M[4], V[4];
    int cn_[4], p0_[4], p1_[4];
    {
        const size_t base = (size_t)row * NC;
#pragma unroll
        for (int k2 = 0; k2 < 4; k2++) {
            int c = l + k2 * 256;
            if (c < NC) {
                U[k2] = z0[base + c];
                cn_[k2] = cnt[c];
                p0_[k2] = off[c];
                p1_[k2] = off[c + 1];
            } else {
                U[k2] = 0.0f; cn_[k2] = -1; p0_[k2] = 0; p1_[k2] = 0;
            }
            M[k2] = 0.0f;
            V[k2] = 0.0f;
        }
    }
    for (int p = l; p < NB; p += 256) thrL[g][p] = ThrG[(size_t)row * NB + p];
    const int myPinv = pinv[row];

    float prev_se = 0.0f, prev_rm = 0.0f;   // per-row leader (l==0) registers
    int prev_am = 0;

    for (int t = 1; t <= 100; t++) {
        const bool odd = (t & 1);
        const float* tuPO = odd ? tuPA : tuPB;
        float* tuPN = odd ? tuPB : tuPA;
        const float bc1 = bcT[2 * (t - 1)];
        const float bc2 = bcT[2 * (t - 1) + 1];

        if (t == 1) {
            // initial step: each group scans prep arrays (verbatim 256-thread path)
            for (int p = tid; p < NB; p += 1024) tuLs[p] = ldgA(&tuPO[p]);
            float bv = -INFINITY;
            int bi = 0x7fffffff;
            for (int i = l; i < NB; i += 256) {
                float pp = 1.0f / ldgA(&seA[i]);
                if (pp > bv || (pp == bv && i < bi)) { bv = pp; bi = i; }
            }
            svg[g][l] = bv; sig[g][l] = bi;
            __syncthreads();
            for (int s = 128; s > 0; s >>= 1) {
                if (l < s) {
                    float v2 = svg[g][l + s]; int i2 = sig[g][l + s];
                    if (v2 > svg[g][l] || (v2 == svg[g][l] && i2 < sig[g][l])) {
                        svg[g][l] = v2; sig[g][l] = i2;
                    }
                }
                __syncthreads();
            }
            const float pmax = svg[g][0];
            const int istar0 = sig[g][0];
            __syncthreads();
            float s2l = 0.0f;
            for (int i = l; i < NB; i += 256) {
                float d = pmax - ptrg[i];
                s2l += (d >= 0.0f) ? 1.0f : -1.0f;
            }
            svg[g][l] = s2l;
            __syncthreads();
            for (int s = 128; s > 0; s >>= 1) {
                if (l < s) svg[g][l] += svg[g][l + s];
                __syncthreads();
            }
            const float s2 = svg[g][0];
            if (l == 0) {
                float Kf = 5.0f * (2048.0f * s2);
                float coef0 = Kf * pmax;
                sc[g][0] = coef0;
                sc[g][1] = ldgA(&seA[istar0]);
                sc[g][2] = ldgA(&rmA[istar0]);
                sci[g][0] = ldgAi(&amA[istar0]);
                sci[g][1] = istar0;
            }
            __syncthreads();
        } else {
            // ---- flat wait: poll the single counter, then read the final key ----
            if (tid == 0) {
                int polls = 0;
                while (ldgAi(&rootCnt[t - 2]) < NBLK) {
                    __builtin_amdgcn_s_sleep(2);
                    if (++polls > (1 << 18)) break;   // fail visibly, never hang
                }
                kShared = ldgAu64(&rootKey[t - 2]);
            }
            __syncthreads();
            // all threads stage tu immediately; group leaders parse concurrently
            const u64 kReg = kShared;
            for (int p = tid; p < NB; p += 1024) tuLs[p] = ldgA(&tuPO[p]);
            if (l == 0) {
                int istarN = (NB - 1) - (int)(kReg & 0xffffffffull);
                sci[g][1] = istarN;
                if (row == istarN) {
                    float pmax = __uint_as_float((unsigned int)(kReg >> 32));
                    // s2 = 2*#{ptrgS <= pmax} - 2048 (exact count form of the +-1 sum)
                    int lo = 0, hi = NB;
                    while (lo < hi) {
                        int mid = (lo + hi) >> 1;
                        if (ptrgS[mid] <= pmax) lo = mid + 1; else hi = mid;
                    }
                    float s2 = (float)(2 * lo - NB);
                    float Kf = 5.0f * (2048.0f * s2);
                    sc[g][0] = Kf * pmax;
                    sc[g][1] = prev_se;
                    sc[g][2] = prev_rm;
                    sci[g][0] = prev_am;
                }
            }
            __syncthreads();
        }
        const float coef = sc[g][0], se_i = sc[g][1], rm_i = sc[g][2];
        const int jstar = sci[g][0], istar = sci[g][1];
        const bool ig2 = (row == istar);

        // ---- gradient + Adam update (registers; LDS-only inner loop) ----
        float nmax = -INFINITY;
        int nidx = 0x7fffffff;
        float ntop = -1000.0f;
#pragma unroll
        for (int k2 = 0; k2 < 4; k2++) {
            int c = l + k2 * 256;
            if (c < NC) {
                float u0 = U[k2];
                float mm = M[k2];
                float vv = V[k2];
                float gg = 0.0f;
                for (int p = p0_[k2]; p < p1_[k2]; p++) {
                    float marg = u0 - tuLs[p];
                    float diff = marg - thrL[g][p];
                    gg += (diff >= 0.0f) ? 1.0f : -1.0f;
                }
                if (ig2) {
                    float e = expf(u0 - rm_i);
                    float S = e / se_i;
                    float dlt = ((c == jstar) ? 1.0f : 0.0f) - S;
                    float t2v = coef * dlt;
                    gg = gg + t2v;
                }
                float t1m = B1F * mm;
                float t2m = C1 * gg;
                mm = t1m + t2m;
                float gg1 = C2 * gg;
                float gg2 = gg1 * gg;
                float t1v = B2F * vv;
                vv = t1v + gg2;
                float mh = mm / bc1;
                float vh = vv / bc2;
                float num = 0.1f * mh;
                float sq = sqrtf(vh);
                float den = sq + 1e-8f;
                float qq = num / den;
                u0 = u0 - qq;
                U[k2] = u0;
                M[k2] = mm;
                V[k2] = vv;
                if (u0 > nmax || (u0 == nmax && c < nidx)) { nmax = u0; nidx = c; }
                if (cn_[k2] == 0) ntop = fmaxf(ntop, u0);
            }
        }

        if (t == 100) break;   // final U is all that matters

        // ---- merged trees A (argmax) + B (masked max), per group: one sync round ----
        float rm_n = 0.0f, tu_n = 0.0f, se_n = 0.0f;
        int am_n = 0;
        svg[g][l] = nmax; sig[g][l] = nidx; tvg[g][l] = ntop;
        __syncthreads();
        if (l < 64) {
            float v = svg[g][l]; int ix = sig[g][l];
            { float v2 = svg[g][l + 128]; int i2 = sig[g][l + 128];
              if (v2 > v || (v2 == v && i2 < ix)) { v = v2; ix = i2; } }
            { float a = svg[g][l + 64]; int ai = sig[g][l + 64];
              float b = svg[g][l + 192]; int bi2 = sig[g][l + 192];
              if (b > a || (b == a && bi2 < ai)) { a = b; ai = bi2; }
              if (a > v || (a == v && ai < ix)) { v = a; ix = ai; } }
#pragma unroll
            for (int s = 32; s > 0; s >>= 1) {
                float v2 = __shfl_xor(v, s);
                int i2 = __shfl_xor(ix, s);
                if (v2 > v || (v2 == v && i2 < ix)) { v = v2; ix = i2; }
            }
            float w = fmaxf(tvg[g][l], tvg[g][l + 128]);
            w = fmaxf(w, fmaxf(tvg[g][l + 64], tvg[g][l + 192]));
#pragma unroll
            for (int s = 32; s > 0; s >>= 1) w = fmaxf(w, __shfl_xor(w, s));
            if (l == 0) { outRmG[g] = v; rm_n = v; am_n = ix; tu_n = w; }
        }
        __syncthreads();
        const float rm_b = outRmG[g];
        // ---- tree C: sel sum from registers (verbatim round-7 pairwise tree) ----
        float sel = 0.0f;
#pragma unroll
        for (int k2 = 0; k2 < 4; k2++) {
            int c = l + k2 * 256;
            if (c < NC) sel += expf(U[k2] - rm_b);
        }
        svg[g][l] = sel;
        __syncthreads();
        if (l < 64) {
            float v = (svg[g][l] + svg[g][l + 128]) + (svg[g][l + 64] + svg[g][l + 192]);
#pragma unroll
            for (int s = 32; s > 0; s >>= 1) v += __shfl_xor(v, s);
            if (l == 0) se_n = v;
        }

        // ---- publish tu + row key; block-combine; flat arrival (max -> add) ----
        if (l == 0) {
            stgA(&tuPN[myPinv], tu_n);
            float pp = 1.0f / se_n;
            kB[g] = ((u64)__float_as_uint(pp) << 32) |
                    (u64)(unsigned int)((NB - 1) - row);
            prev_se = se_n; prev_rm = rm_n; prev_am = am_n;
        }
        __syncthreads();   // kB visible; leaders' tu stores drained by sync's vmcnt
        if (tid == 0) {
            u64 key = kB[0];
            if (kB[1] > key) key = kB[1];
            if (kB[2] > key) key = kB[2];
            if (kB[3] > key) key = kB[3];
            atomicMax(&rootKey[t - 1], key);
            asm volatile("s_waitcnt vmcnt(0)" ::: "memory");   // max landed before gate
            __hip_atomic_fetch_add(&rootCnt[t - 1], 1,
                                   __ATOMIC_RELAXED, __HIP_MEMORY_SCOPE_AGENT);
        }
    }

    {
        const size_t base = (size_t)row * NC;
#pragma unroll
        for (int k2 = 0; k2 < 4; k2++) {
            int c = l + k2 * 256;
            if (c < NC) uout[base + c] = U[k2];
        }
    }
}

// ---------------- fuse: out = A + clamp(median5(A,P1..P4) - A, +-0.08) ----------------
__global__ void k_fuse5(const float* __restrict__ a, const float* __restrict__ p1,
                        const float* __restrict__ p2, const float* __restrict__ p3,
                        const float* __restrict__ p4, float* __restrict__ out, int n) {
    const float CL = 0.08f;
    int i = blockIdx.x * 256 + threadIdx.x;
    if (i < n) {
        float v0 = a[i], v1 = p1[i], v2 = p2[i], v3 = p3[i], v4 = p4[i];
        float vv[5] = {v0, v1, v2, v3, v4};
#pragma unroll
        for (int k = 1; k < 5; k++) {
            float key = vv[k];
            int j = k - 1;
            while (j >= 0 && vv[j] > key) { vv[j + 1] = vv[j]; j--; }
            vv[j + 1] = key;
        }
        float med = vv[2];
        float d = med - v0;
        d = fminf(fmaxf(d, -CL), CL);
        out[i] = v0 + d;
    }
}

extern "C" void kernel_launch(void* const* d_in, const int* in_sizes, int n_in,
                              void* d_out, int out_size, void* d_ws, size_t ws_size,
                              hipStream_t stream) {
    (void)in_sizes; (void)n_in; (void)out_size; (void)ws_size;
    const float* x = (const float*)d_in[0];
    const float* W = (const float*)d_in[1];
    const float* bias = (const float*)d_in[2];
    float* out = (float*)d_out;

    const size_t NE = (size_t)NB * NC;
    float* zm    = (float*)d_ws;
    float* t0    = zm + NE;                 // 5 trajectory buffers
    float* t1    = t0 + NE;
    float* t2    = t1 + NE;
    float* t3    = t2 + NE;
    float* t4    = t3 + NE;
    float* ThrG  = t4 + NE;                 // 2048*2048
    float* tz    = ThrG + (size_t)NB * NB;
    float* ptrg  = tz + NB;
    float* ptrgS = ptrg + NB;
    float* seA   = ptrgS + NB;
    float* rmA   = seA + NB;
    float* tuPA  = rmA + NB;
    float* tuPB  = tuPA + NB;
    float* bcT   = tuPB + NB;               // 200 floats (bias-correction table)
    int* amA   = (int*)(bcT + 256);
    int* yv    = amA + NB;
    int* jidx  = yv + NB;
    int* pinv  = jidx + NB;
    int* cnt   = pinv + NB;
    int* off   = cnt + 1024;
    int* pos   = off + 1024;
    int* rootCnt = pos + 1024;              // 128 ints  (flat barrier counters)
    u64* rootKey = (u64*)(rootCnt + 128);   // 128 u64  (flat barrier keys; 8B-aligned)

    // host-side bias corrections, exact same powf as round-0 (host libm)
    static float h_bc[200];
    static int bc_init = 0;
    if (!bc_init) {
        for (int t = 1; t <= 100; t++) {
            h_bc[2 * (t - 1)]     = 1.0f - powf(0.9f, (float)t);
            h_bc[2 * (t - 1) + 1] = 1.0f - powf(0.999f, (float)t);
        }
        bc_init = 1;
    }
    hipMemcpyAsync(bcT, h_bc, 200 * sizeof(float), hipMemcpyHostToDevice, stream);

    float* traj[5] = {t0, t1, t2, t3, t4};
    const int PCs[5] = {0, 32, 24, 16, 10};   // monolithic, Kc=512,384,256,160
    const int nblk = (int)((NE + 255) / 256);
    const size_t barBytes = 128 * sizeof(int) + 128 * sizeof(u64);

    for (int pass = 0; pass < 5; pass++) {
        k_gemm<<<dim3(16, 32), 256, 0, stream>>>(x, W, bias, zm, PCs[pass]);
        hipMemsetAsync(cnt, 0, 1024 * sizeof(int), stream);
        hipMemsetAsync(rootCnt, 0, barBytes, stream);
        k_rowstats<<<NB, 256, 0, stream>>>(zm, yv, ptrg, seA, rmA, amA);
        k_hist<<<8, 256, 0, stream>>>(yv, cnt);
        k_group<<<1, 1024, 0, stream>>>(yv, cnt, off, pos, jidx, pinv);
        k_sort<<<1, 1024, 0, stream>>>(ptrg, ptrgS);
        k_preptz<<<NB, 256, 0, stream>>>(zm, cnt, pinv, tz, tuPA);
        k_thr<<<NB, 256, 0, stream>>>(zm, tz, yv, jidx, ThrG);

        k_adam<<<NBLK, 1024, 0, stream>>>(zm, traj[pass], ThrG, ptrg, ptrgS,
                                          cnt, off, jidx, pinv,
                                          seA, rmA, amA, tuPA, tuPB,
                                          bcT, rootCnt, rootKey);
    }

    k_fuse5<<<nblk, 256, 0, stream>>>(t0, t1, t2, t3, t4, out, (int)NE);
}

// Round 12
// 9294.292 us; speedup vs baseline: 1.7502x; 1.7502x over previous
//
#include <hip/hip_runtime.h>
#include <math.h>

#pragma clang fp contract(off)

#define NB 2048
#define NC 1000
#define NK 2048
#define RPB 4                  // rows per block (parallel thread-groups, NOT serialized)
#define NBLK (NB / RPB)        // 512 blocks = 2 blocks/CU * 256 CUs (guaranteed co-resident)
#define NLEAF 16               // 512 blocks / 32 per leaf

typedef unsigned long long u64;

// ---------------- GEMM: fp32 fold-left ascending-k with K-panel folds of PC chunks ------
__global__ __launch_bounds__(256) void k_gemm(const float* __restrict__ x,
                                              const float* __restrict__ W,
                                              const float* __restrict__ bias,
                                              float* __restrict__ z, int PC) {
    __shared__ float As[16][64];
    __shared__ float Bs[16][64];
    const int tid = threadIdx.x;
    const int m0 = blockIdx.y * 64, n0 = blockIdx.x * 64;
    const int tx = tid & 15, ty = tid >> 4;
    float accT[4][4];
    float accB[4][4];
#pragma unroll
    for (int i = 0; i < 4; i++)
#pragma unroll
        for (int j = 0; j < 4; j++) { accT[i][j] = 0.0f; accB[i][j] = 0.0f; }

    for (int kb = 0; kb < 128; kb++) {
        if (PC > 0 && kb > 0 && (kb % PC) == 0) {
#pragma unroll
            for (int i = 0; i < 4; i++)
#pragma unroll
                for (int j = 0; j < 4; j++) { accT[i][j] += accB[i][j]; accB[i][j] = 0.0f; }
        }
        const int k0 = kb * 16;
        {
            int row = tid >> 2, kg = tid & 3;
            const float4 a = *(const float4*)(x + (size_t)(m0 + row) * NK + k0 + kg * 4);
            As[kg * 4 + 0][row] = a.x;
            As[kg * 4 + 1][row] = a.y;
            As[kg * 4 + 2][row] = a.z;
            As[kg * 4 + 3][row] = a.w;
        }
        {
            int rowk = tid >> 4, c4 = tid & 15;
            int cbase = n0 + c4 * 4;
            const float* wp = W + (size_t)(k0 + rowk) * NC + cbase;
#pragma unroll
            for (int j = 0; j < 4; j++)
                Bs[rowk][c4 * 4 + j] = (cbase + j < NC) ? wp[j] : 0.0f;
        }
        __syncthreads();
#pragma unroll
        for (int kk = 0; kk < 16; kk++) {
            float a[4], bb[4];
#pragma unroll
            for (int i = 0; i < 4; i++) a[i] = As[kk][ty * 4 + i];
#pragma unroll
            for (int j = 0; j < 4; j++) bb[j] = Bs[kk][tx * 4 + j];
#pragma unroll
            for (int i = 0; i < 4; i++)
#pragma unroll
                for (int j = 0; j < 4; j++) accB[i][j] = fmaf(a[i], bb[j], accB[i][j]);
        }
        __syncthreads();
    }
#pragma unroll
    for (int i = 0; i < 4; i++) {
        int r = m0 + ty * 4 + i;
#pragma unroll
        for (int j = 0; j < 4; j++) {
            int c = n0 + tx * 4 + j;
            if (c < NC) {
                float s = accT[i][j] + accB[i][j];
                z[(size_t)r * NC + c] = s + bias[c];
            }
        }
    }
}

// ---------------- per-row stats ----------------
__global__ __launch_bounds__(256) void k_rowstats(const float* __restrict__ z,
                                                  int* __restrict__ y,
                                                  float* __restrict__ ptrg,
                                                  float* __restrict__ se,
                                                  float* __restrict__ rm,
                                                  int* __restrict__ am) {
    __shared__ float sv[256];
    __shared__ int si[256];
    const int tid = threadIdx.x, row = blockIdx.x;
    const float* zr = z + (size_t)row * NC;
    float bv = -INFINITY;
    int bi = 0x7fffffff;
    for (int c = tid; c < NC; c += 256) {
        float zz = zr[c];
        if (zz > bv) { bv = zz; bi = c; }
    }
    sv[tid] = bv; si[tid] = bi;
    __syncthreads();
    for (int s = 128; s > 0; s >>= 1) {
        if (tid < s) {
            float v2 = sv[tid + s]; int i2 = si[tid + s];
            if (v2 > sv[tid] || (v2 == sv[tid] && i2 < si[tid])) { sv[tid] = v2; si[tid] = i2; }
        }
        __syncthreads();
    }
    const float rmx = sv[0];
    const int amx = si[0];
    __syncthreads();
    float sl = 0.0f;
    for (int c = tid; c < NC; c += 256) sl += expf(zr[c] - rmx);
    sv[tid] = sl;
    __syncthreads();
    for (int s = 128; s > 0; s >>= 1) {
        if (tid < s) sv[tid] += sv[tid + s];
        __syncthreads();
    }
    if (tid == 0) {
        float s0 = sv[0];
        y[row] = amx; ptrg[row] = 1.0f / s0;
        se[row] = s0; rm[row] = rmx; am[row] = amx;
    }
}

__global__ void k_hist(const int* __restrict__ y, int* __restrict__ cnt) {
    int i = blockIdx.x * 256 + threadIdx.x;
    if (i < NB) atomicAdd(&cnt[y[i]], 1);
}
__global__ __launch_bounds__(1024) void k_group(const int* __restrict__ y,
                                                const int* __restrict__ cnt,
                                                int* __restrict__ off,
                                                int* __restrict__ pos,
                                                int* __restrict__ jidx,
                                                int* __restrict__ pinv) {
    __shared__ int s[1024];
    const int tid = threadIdx.x;
    int myc = (tid < NC) ? cnt[tid] : 0;
    s[tid] = myc;
    __syncthreads();
    for (int d = 1; d < 1024; d <<= 1) {
        int add = (tid >= d) ? s[tid - d] : 0;
        __syncthreads();
        s[tid] += add;
        __syncthreads();
    }
    if (tid < NC) {
        int excl = s[tid] - myc;
        off[tid] = excl;
        pos[tid] = excl;
    }
    if (tid == 0) off[NC] = NB;
    __syncthreads();
    for (int j = tid; j < NB; j += 1024) {
        int c = y[j];
        int p = atomicAdd(&pos[c], 1);
        jidx[p] = j;
        pinv[j] = p;
    }
}

// ---------------- bitonic sort of ptrg (2048) -> ptrgS, once per pass ----------------
__global__ __launch_bounds__(1024) void k_sort(const float* __restrict__ ptrg,
                                               float* __restrict__ ptrgS) {
    __shared__ float ps[2048];
    const int tid = threadIdx.x;
    ps[tid] = ptrg[tid];
    ps[tid + 1024] = ptrg[tid + 1024];
    __syncthreads();
    for (int k = 2; k <= 2048; k <<= 1) {
        for (int j = k >> 1; j > 0; j >>= 1) {
            int i1 = ((tid & ~(j - 1)) << 1) | (tid & (j - 1));
            int i2 = i1 | j;
            bool up = ((i1 & k) == 0);
            float a = ps[i1], b = ps[i2];
            if ((a > b) == up) { ps[i1] = b; ps[i2] = a; }
            __syncthreads();
        }
    }
    ptrgS[tid] = ps[tid];
    ptrgS[tid + 1024] = ps[tid + 1024];
}

// tz + initial permuted tu
__global__ __launch_bounds__(256) void k_preptz(const float* __restrict__ z,
                                                const int* __restrict__ cnt,
                                                const int* __restrict__ pinv,
                                                float* __restrict__ tz,
                                                float* __restrict__ tuP) {
    __shared__ float sv[256];
    const int tid = threadIdx.x, row = blockIdx.x;
    const float* zr = z + (size_t)row * NC;
    float tm = -1000.0f;
    for (int c = tid; c < NC; c += 256) {
        float zz = zr[c];
        if (cnt[c] == 0) tm = fmaxf(tm, zz);
    }
    sv[tid] = tm;
    __syncthreads();
    for (int s = 128; s > 0; s >>= 1) {
        if (tid < s) sv[tid] = fmaxf(sv[tid], sv[tid + s]);
        __syncthreads();
    }
    if (tid == 0) { tz[row] = sv[0]; tuP[pinv[row]] = sv[0]; }
}

__global__ __launch_bounds__(256) void k_thr(const float* __restrict__ z,
                                             const float* __restrict__ tz,
                                             const int* __restrict__ y,
                                             const int* __restrict__ jidx,
                                             float* __restrict__ ThrG) {
    const int tid = threadIdx.x, a = blockIdx.x;
    const float PIF = 3.14159265358979323846f;
    const float* zr = z + (size_t)a * NC;
    for (int p = tid; p < NB; p += 256) {
        int j = jidx[p];
        int c = y[j];
        float L = zr[c] - tz[j];
        float q = L / 6.0f;
        float fq = floorf(q);
        float fh = fq + 0.5f;
        float latr = fh * 6.0f;
        float d1 = L - latr;
        float d2 = 2.0f * d1;
        float d3 = d2 / 6.0f;
        float d4 = 1.0f - d3;
        float d5 = PIF * d4;
        float sn = sinf(d5);
        float p6 = 6.0f * sn;
        float thr = L - p6;
        ThrG[(size_t)a * NB + p] = thr;
    }
}

// -------- agent-scope (device-coherent) access helpers --------
__device__ __forceinline__ float ldgA(const float* p) {
    return __hip_atomic_load(p, __ATOMIC_RELAXED, __HIP_MEMORY_SCOPE_AGENT);
}
__device__ __forceinline__ int ldgAi(const int* p) {
    return __hip_atomic_load(p, __ATOMIC_RELAXED, __HIP_MEMORY_SCOPE_AGENT);
}
__device__ __forceinline__ u64 ldgAu64(const u64* p) {
    return __hip_atomic_load(p, __ATOMIC_RELAXED, __HIP_MEMORY_SCOPE_AGENT);
}
__device__ __forceinline__ void stgA(float* p, float v) {
    __hip_atomic_store(p, v, __ATOMIC_RELAXED, __HIP_MEMORY_SCOPE_AGENT);
}
__device__ __forceinline__ void stgAu64(u64* p, u64 v) {
    __hip_atomic_store(p, v, __ATOMIC_RELAXED, __HIP_MEMORY_SCOPE_AGENT);
}

// ---------------- all 100 Adam steps; 4 rows per block in parallel thread-groups --------
// Group g = tid>>8 owns row 4*bid+g with its own 256-thread trees (shape-identical to the
// 1-row kernel). tuLs staged once per block (shared). One arrival per block: 4 row keys
// max-combined in LDS -> leaf atomicMax -> counted adds; 16th root arrival fans the final
// key to 16 mirror words (key==flag==payload). istar's row-group derives coef locally.
__global__ __launch_bounds__(1024, 8) void k_adam(
    const float* __restrict__ z0,
    float* __restrict__ uout,
    const float* __restrict__ ThrG,
    const float* __restrict__ ptrg,
    const float* __restrict__ ptrgS,
    const int* __restrict__ cnt,
    const int* __restrict__ off,
    const int* __restrict__ jidx,
    const int* __restrict__ pinv,
    const float* __restrict__ seA, const float* __restrict__ rmA,
    const int* __restrict__ amA,
    float* __restrict__ tuPA, float* __restrict__ tuPB,
    const float* __restrict__ bcT,
    int* __restrict__ leafCnt, int* __restrict__ rootCnt,
    u64* __restrict__ leafKey, u64* __restrict__ rootKey,
    u64* __restrict__ keyMir) {
    __shared__ float tuLs[NB];          // permuted tu, shared by 4 rows (8 KB)
    __shared__ float thrL[RPB][NB];     // 4 ThrG rows, staged ONCE (32 KB)
    __shared__ float svg[RPB][256];
    __shared__ int   sig[RPB][256];
    __shared__ float tvg[RPB][256];
    __shared__ float sc[RPB][3];        // coef, se_i, rm_i per row
    __shared__ int   sci[RPB][2];       // jstar, istar per row
    __shared__ float outRmG[RPB];
    __shared__ u64   kB[RPB];
    __shared__ u64   kShared;
    const int tid = threadIdx.x;
    const int g = tid >> 8;             // row group 0..3
    const int l = tid & 255;            // lane within group
    const int row = blockIdx.x * RPB + g;
    const int leaf = blockIdx.x >> 5;   // 16 leaves x 32 blocks
    const float B1F = 0.9f;
    const float C1 = (float)(1.0 - 0.9);
    const float B2F = 0.999f;
    const float C2 = (float)(1.0 - 0.999);

    float U[4], M[4], V[4];
    int cn_[4], p0_[4], p1_[4];
    {
        const size_t base = (size_t)row * NC;
#pragma unroll
        for (int k2 = 0; k2 < 4; k2++) {
            int c = l + k2 * 256;
            if (c < NC) {
                U[k2] = z0[base + c];
                cn_[k2] = cnt[c];
                p0_[k2] = off[c];
                p1_[k2] = off[c + 1];
            } else {
                U[k2] = 0.0f; cn_[k2] = -1; p0_[k2] = 0; p1_[k2] = 0;
            }
            M[k2] = 0.0f;
            V[k2] = 0.0f;
        }
    }
    for (int p = l; p < NB; p += 256) thrL[g][p] = ThrG[(size_t)row * NB + p];
    const int myPinv = pinv[row];

    float prev_se = 0.0f, prev_rm = 0.0f;   // per-row leader (l==0) registers
    int prev_am = 0;

    for (int t = 1; t <= 100; t++) {
        const bool odd = (t & 1);
        const float* tuPO = odd ? tuPA : tuPB;
        float* tuPN = odd ? tuPB : tuPA;
        const float bc1 = bcT[2 * (t - 1)];
        const float bc2 = bcT[2 * (t - 1) + 1];

        if (t == 1) {
            // initial step: each group scans prep arrays (verbatim 256-thread path)
            for (int p = tid; p < NB; p += 1024) tuLs[p] = ldgA(&tuPO[p]);
            float bv = -INFINITY;
            int bi = 0x7fffffff;
            for (int i = l; i < NB; i += 256) {
                float pp = 1.0f / ldgA(&seA[i]);
                if (pp > bv || (pp == bv && i < bi)) { bv = pp; bi = i; }
            }
            svg[g][l] = bv; sig[g][l] = bi;
            __syncthreads();
            for (int s = 128; s > 0; s >>= 1) {
                if (l < s) {
                    float v2 = svg[g][l + s]; int i2 = sig[g][l + s];
                    if (v2 > svg[g][l] || (v2 == svg[g][l] && i2 < sig[g][l])) {
                        svg[g][l] = v2; sig[g][l] = i2;
                    }
                }
                __syncthreads();
            }
            const float pmax = svg[g][0];
            const int istar0 = sig[g][0];
            __syncthreads();
            float s2l = 0.0f;
            for (int i = l; i < NB; i += 256) {
                float d = pmax - ptrg[i];
                s2l += (d >= 0.0f) ? 1.0f : -1.0f;
            }
            svg[g][l] = s2l;
            __syncthreads();
            for (int s = 128; s > 0; s >>= 1) {
                if (l < s) svg[g][l] += svg[g][l + s];
                __syncthreads();
            }
            const float s2 = svg[g][0];
            if (l == 0) {
                float Kf = 5.0f * (2048.0f * s2);
                float coef0 = Kf * pmax;
                sc[g][0] = coef0;
                sc[g][1] = ldgA(&seA[istar0]);
                sc[g][2] = ldgA(&rmA[istar0]);
                sci[g][0] = ldgAi(&amA[istar0]);
                sci[g][1] = istar0;
            }
            __syncthreads();
        } else {
            // ---- wait on leaf mirror; wake-up load IS the key payload ----
            if (tid == 0) {
                const u64* mp = &keyMir[(size_t)(t - 2) * NLEAF + leaf];
                u64 kReg = 0ull;
                int polls = 0;
                while ((kReg = ldgAu64(mp)) == 0ull) {
                    __builtin_amdgcn_s_sleep(1);
                    if (++polls > (1 << 18)) break;   // fail visibly, never hang
                }
                kShared = kReg;
            }
            __syncthreads();
            // all threads stage tu immediately; group leaders parse concurrently
            const u64 kReg = kShared;
            for (int p = tid; p < NB; p += 1024) tuLs[p] = ldgA(&tuPO[p]);
            if (l == 0) {
                int istarN = (NB - 1) - (int)(kReg & 0xffffffffull);
                sci[g][1] = istarN;
                if (row == istarN) {
                    float pmax = __uint_as_float((unsigned int)(kReg >> 32));
                    // s2 = 2*#{ptrgS <= pmax} - 2048 (exact count form of the +-1 sum)
                    int lo = 0, hi = NB;
                    while (lo < hi) {
                        int mid = (lo + hi) >> 1;
                        if (ptrgS[mid] <= pmax) lo = mid + 1; else hi = mid;
                    }
                    float s2 = (float)(2 * lo - NB);
                    float Kf = 5.0f * (2048.0f * s2);
                    sc[g][0] = Kf * pmax;
                    sc[g][1] = prev_se;
                    sc[g][2] = prev_rm;
                    sci[g][0] = prev_am;
                }
            }
            __syncthreads();
        }
        const float coef = sc[g][0], se_i = sc[g][1], rm_i = sc[g][2];
        const int jstar = sci[g][0], istar = sci[g][1];
        const bool ig2 = (row == istar);

        // ---- gradient + Adam update (registers; LDS-only inner loop) ----
        float nmax = -INFINITY;
        int nidx = 0x7fffffff;
        float ntop = -1000.0f;
#pragma unroll
        for (int k2 = 0; k2 < 4; k2++) {
            int c = l + k2 * 256;
            if (c < NC) {
                float u0 = U[k2];
                float mm = M[k2];
                float vv = V[k2];
                float gg = 0.0f;
                for (int p = p0_[k2]; p < p1_[k2]; p++) {
                    float marg = u0 - tuLs[p];
                    float diff = marg - thrL[g][p];
                    gg += (diff >= 0.0f) ? 1.0f : -1.0f;
                }
                if (ig2) {
                    float e = expf(u0 - rm_i);
                    float S = e / se_i;
                    float dlt = ((c == jstar) ? 1.0f : 0.0f) - S;
                    float t2v = coef * dlt;
                    gg = gg + t2v;
                }
                float t1m = B1F * mm;
                float t2m = C1 * gg;
                mm = t1m + t2m;
                float gg1 = C2 * gg;
                float gg2 = gg1 * gg;
                float t1v = B2F * vv;
                vv = t1v + gg2;
                float mh = mm / bc1;
                float vh = vv / bc2;
                float num = 0.1f * mh;
                float sq = sqrtf(vh);
                float den = sq + 1e-8f;
                float qq = num / den;
                u0 = u0 - qq;
                U[k2] = u0;
                M[k2] = mm;
                V[k2] = vv;
                if (u0 > nmax || (u0 == nmax && c < nidx)) { nmax = u0; nidx = c; }
                if (cn_[k2] == 0) ntop = fmaxf(ntop, u0);
            }
        }

        if (t == 100) break;   // final U is all that matters

        // ---- merged trees A (argmax) + B (masked max), per group: one sync round ----
        float rm_n = 0.0f, tu_n = 0.0f, se_n = 0.0f;
        int am_n = 0;
        svg[g][l] = nmax; sig[g][l] = nidx; tvg[g][l] = ntop;
        __syncthreads();
        if (l < 64) {
            float v = svg[g][l]; int ix = sig[g][l];
            { float v2 = svg[g][l + 128]; int i2 = sig[g][l + 128];
              if (v2 > v || (v2 == v && i2 < ix)) { v = v2; ix = i2; } }
            { float a = svg[g][l + 64]; int ai = sig[g][l + 64];
              float b = svg[g][l + 192]; int bi2 = sig[g][l + 192];
              if (b > a || (b == a && bi2 < ai)) { a = b; ai = bi2; }
              if (a > v || (a == v && ai < ix)) { v = a; ix = ai; } }
#pragma unroll
            for (int s = 32; s > 0; s >>= 1) {
                float v2 = __shfl_xor(v, s);
                int i2 = __shfl_xor(ix, s);
                if (v2 > v || (v2 == v && i2 < ix)) { v = v2; ix = i2; }
            }
            float w = fmaxf(tvg[g][l], tvg[g][l + 128]);
            w = fmaxf(w, fmaxf(tvg[g][l + 64], tvg[g][l + 192]));
#pragma unroll
            for (int s = 32; s > 0; s >>= 1) w = fmaxf(w, __shfl_xor(w, s));
            if (l == 0) { outRmG[g] = v; rm_n = v; am_n = ix; tu_n = w; }
        }
        __syncthreads();
        const float rm_b = outRmG[g];
        // ---- tree C: sel sum — hybrid fold (verbatim pairwise order) ----
        float sel = 0.0f;
#pragma unroll
        for (int k2 = 0; k2 < 4; k2++) {
            int c = l + k2 * 256;
            if (c < NC) sel += expf(U[k2] - rm_b);
        }
        svg[g][l] = sel;
        __syncthreads();
        if (l < 64) {
            float v = (svg[g][l] + svg[g][l + 128]) + (svg[g][l + 64] + svg[g][l + 192]);
#pragma unroll
            for (int s = 32; s > 0; s >>= 1) v += __shfl_xor(v, s);
            if (l == 0) se_n = v;
        }

        // ---- publish tu + row key; block-combine keys; hierarchical arrival ----
        if (l == 0) {
            stgA(&tuPN[myPinv], tu_n);
            float pp = 1.0f / se_n;
            kB[g] = ((u64)__float_as_uint(pp) << 32) |
                    (u64)(unsigned int)((NB - 1) - row);
            prev_se = se_n; prev_rm = rm_n; prev_am = am_n;
        }
        __syncthreads();   // kB visible; all leaders' tu stores drained (per-wave vmcnt)
        if (tid == 0) {
            u64 key = kB[0];
            if (kB[1] > key) key = kB[1];
            if (kB[2] > key) key = kB[2];
            if (kB[3] > key) key = kB[3];
            u64* lkp = &leafKey[(size_t)(t - 1) * NLEAF + leaf];
            atomicMax(lkp, key);
            asm volatile("s_waitcnt vmcnt(0)" ::: "memory");
            int old = __hip_atomic_fetch_add(&leafCnt[(t - 1) * NLEAF + leaf], 1,
                                             __ATOMIC_RELAXED, __HIP_MEMORY_SCOPE_AGENT);
            if (old == 31) {
                u64 lk = ldgAu64(lkp);                          // all 32 maxes landed
                atomicMax(&rootKey[t - 1], lk);
                asm volatile("s_waitcnt vmcnt(0)" ::: "memory");
                int ro = __hip_atomic_fetch_add(&rootCnt[t - 1], 1,
                                                __ATOMIC_RELAXED, __HIP_MEMORY_SCOPE_AGENT);
                if (ro == NLEAF - 1) {
                    u64 fin = ldgAu64(&rootKey[t - 1]);         // all 16 maxes landed
                    u64* mir = &keyMir[(size_t)(t - 1) * NLEAF];
                    for (int lf = 0; lf < NLEAF; lf++) stgAu64(&mir[lf], fin);
                }
            }
        }
    }

    {
        const size_t base = (size_t)row * NC;
#pragma unroll
        for (int k2 = 0; k2 < 4; k2++) {
            int c = l + k2 * 256;
            if (c < NC) uout[base + c] = U[k2];
        }
    }
}

// ---------------- fuse: out = A + clamp(median5(A,P1..P4) - A, +-0.08) ----------------
__global__ void k_fuse5(const float* __restrict__ a, const float* __restrict__ p1,
                        const float* __restrict__ p2, const float* __restrict__ p3,
                        const float* __restrict__ p4, float* __restrict__ out, int n) {
    const float CL = 0.08f;
    int i = blockIdx.x * 256 + threadIdx.x;
    if (i < n) {
        float v0 = a[i], v1 = p1[i], v2 = p2[i], v3 = p3[i], v4 = p4[i];
        float vv[5] = {v0, v1, v2, v3, v4};
#pragma unroll
        for (int k = 1; k < 5; k++) {
            float key = vv[k];
            int j = k - 1;
            while (j >= 0 && vv[j] > key) { vv[j + 1] = vv[j]; j--; }
            vv[j + 1] = key;
        }
        float med = vv[2];
        float d = med - v0;
        d = fminf(fmaxf(d, -CL), CL);
        out[i] = v0 + d;
    }
}

extern "C" void kernel_launch(void* const* d_in, const int* in_sizes, int n_in,
                              void* d_out, int out_size, void* d_ws, size_t ws_size,
                              hipStream_t stream) {
    (void)in_sizes; (void)n_in; (void)out_size; (void)ws_size;
    const float* x = (const float*)d_in[0];
    const float* W = (const float*)d_in[1];
    const float* bias = (const float*)d_in[2];
    float* out = (float*)d_out;

    const size_t NE = (size_t)NB * NC;
    float* zm    = (float*)d_ws;
    float* t0    = zm + NE;                 // 5 trajectory buffers
    float* t1    = t0 + NE;
    float* t2    = t1 + NE;
    float* t3    = t2 + NE;
    float* t4    = t3 + NE;
    float* ThrG  = t4 + NE;                 // 2048*2048
    float* tz    = ThrG + (size_t)NB * NB;
    float* ptrg  = tz + NB;
    float* ptrgS = ptrg + NB;
    float* seA   = ptrgS + NB;
    float* rmA   = seA + NB;
    float* tuPA  = rmA + NB;
    float* tuPB  = tuPA + NB;
    float* bcT   = tuPB + NB;               // 200 floats (bias-correction table)
    int* amA   = (int*)(bcT + 256);
    int* yv    = amA + NB;
    int* jidx  = yv + NB;
    int* pinv  = jidx + NB;
    int* cnt   = pinv + NB;
    int* off   = cnt + 1024;
    int* pos   = off + 1024;
    int* leafCnt = pos + 1024;              // 100*16 ints (padded 6400)
    int* rootCnt = leafCnt + 6400;          // 128 ints
    u64* leafKey = (u64*)(rootCnt + 128);   // 100*16 u64 (padded region)
    u64* rootKey = leafKey + 6400;          // 128 u64
    u64* keyMir  = rootKey + 128;           // 100*16 u64 (mirror = flag + payload)

    // host-side bias corrections, exact same powf as round-0 (host libm)
    static float h_bc[200];
    static int bc_init = 0;
    if (!bc_init) {
        for (int t = 1; t <= 100; t++) {
            h_bc[2 * (t - 1)]     = 1.0f - powf(0.9f, (float)t);
            h_bc[2 * (t - 1) + 1] = 1.0f - powf(0.999f, (float)t);
        }
        bc_init = 1;
    }
    hipMemcpyAsync(bcT, h_bc, 200 * sizeof(float), hipMemcpyHostToDevice, stream);

    float* traj[5] = {t0, t1, t2, t3, t4};
    const int PCs[5] = {0, 32, 24, 16, 10};   // monolithic, Kc=512,384,256,160
    const int nblk = (int)((NE + 255) / 256);
    const size_t barBytes = (6400 + 128) * sizeof(int) + (6400 + 128 + 6400) * sizeof(u64);

    for (int pass = 0; pass < 5; pass++) {
        k_gemm<<<dim3(16, 32), 256, 0, stream>>>(x, W, bias, zm, PCs[pass]);
        hipMemsetAsync(cnt, 0, 1024 * sizeof(int), stream);
        hipMemsetAsync(leafCnt, 0, barBytes, stream);
        k_rowstats<<<NB, 256, 0, stream>>>(zm, yv, ptrg, seA, rmA, amA);
        k_hist<<<8, 256, 0, stream>>>(yv, cnt);
        k_group<<<1, 1024, 0, stream>>>(yv, cnt, off, pos, jidx, pinv);
        k_sort<<<1, 1024, 0, stream>>>(ptrg, ptrgS);
        k_preptz<<<NB, 256, 0, stream>>>(zm, cnt, pinv, tz, tuPA);
        k_thr<<<NB, 256, 0, stream>>>(zm, tz, yv, jidx, ThrG);

        k_adam<<<NBLK, 1024, 0, stream>>>(zm, traj[pass], ThrG, ptrg, ptrgS,
                                          cnt, off, jidx, pinv,
                                          seA, rmA, amA, tuPA, tuPB,
                                          bcT, leafCnt, rootCnt,
                                          leafKey, rootKey, keyMir);
    }

    k_fuse5<<<nblk, 256, 0, stream>>>(t0, t1, t2, t3, t4, out, (int)NE);
}